// Round 9
// baseline (16896.791 us; speedup 1.0000x reference)
//
#include <hip/hip_runtime.h>
#include <math.h>

#define SEQL 2048
#define H 1024
#define G3 3072
#define SENT 1.0e30f

typedef __fp16   fp16x2  __attribute__((ext_vector_type(2)));
typedef _Float16 half2_t __attribute__((ext_vector_type(2)));

__device__ __forceinline__ float sigmoidf_(float x){ return 1.0f/(1.0f+expf(-x)); }

// pack two f32 -> f16x2 word (round-toward-zero packed cvt)
__device__ __forceinline__ uint32_t pk_u(float a, float b){
  fp16x2 h = __builtin_amdgcn_cvt_pkrtz(a, b);
  union{fp16x2 h; uint32_t u;} c; c.h = h; return c.u;
}
__device__ __forceinline__ half2_t u_as_h2(uint32_t x){
  union{half2_t h; uint32_t u;} c; c.u = x; return c.h;
}

// L2-scope load (bypass L1): same-XCD producer/consumer visibility, ~250cy.
__device__ __forceinline__ float4 ld_l2(const float* p){
  float4 r;
  asm volatile("global_load_dwordx4 %0, %1, off sc0\n\t"
               "s_waitcnt vmcnt(0)"
               : "=&v"(r) : "v"(p) : "memory");
  return r;
}
// Coherence-point load (bypass L1+L2): cross-XCD-safe fallback.
__device__ __forceinline__ float4 ld_uc(const float* p){
  float4 r;
  asm volatile("global_load_dwordx4 %0, %1, off sc0 sc1\n\t"
               "s_waitcnt vmcnt(0)"
               : "=&v"(r) : "v"(p) : "memory");
  return r;
}
__device__ __forceinline__ void st_l2_2(float* p, float2 v){
  asm volatile("global_store_dwordx2 %0, %1, off sc0"
               :: "v"(p), "v"(v) : "memory");
}
__device__ __forceinline__ void st_uc_2(float* p, float2 v){
  asm volatile("global_store_dwordx2 %0, %1, off sc0 sc1"
               :: "v"(p), "v"(v) : "memory");
}

__global__ __launch_bounds__(256) void init_sent(float* p, int n4){
  int i = blockIdx.x*256 + threadIdx.x;
  if (i < n4) ((float4*)p)[i] = make_float4(SENT,SENT,SENT,SENT);
}

__global__ __launch_bounds__(256) void embed_kernel(const int* __restrict__ ids,
                                                    const float* __restrict__ emb,
                                                    float* __restrict__ out){
  int t = blockIdx.x;
  int id = ids[t];
  const float4* src = (const float4*)(emb + (size_t)id*H);
  float4* dst = (float4*)(out + (size_t)t*H);
  float4 v = (id == 1) ? make_float4(0.f,0.f,0.f,0.f) : src[threadIdx.x];
  dst[threadIdx.x] = v;
}

__global__ __launch_bounds__(256) void gemm_kernel(const float* __restrict__ A,
  const float* __restrict__ WF, const float* __restrict__ WR,
  const float* __restrict__ bF, const float* __restrict__ bR,
  float* __restrict__ gxF, float* __restrict__ gxR)
{
  __shared__ float As[16][68];
  __shared__ float Bs[16][68];
  const int tid = threadIdx.x;
  const int n0 = blockIdx.x * 64;
  const int m0 = blockIdx.y * 64;
  const int dir = (n0 >= G3);
  const float* B    = dir ? WR : WF;
  const float* bias = dir ? bR : bF;
  float* C          = dir ? gxR : gxF;
  const int j0 = dir ? (n0 - G3) : n0;

  const int lr = tid >> 2;
  const int lc = (tid & 3) * 4;
  const int tx = tid & 15;
  const int ty = tid >> 4;

  float acc[4][4] = {};

  for (int k0 = 0; k0 < H; k0 += 16){
    float4 av = *(const float4*)(A + (size_t)(m0+lr)*H + k0 + lc);
    float4 bv = *(const float4*)(B + (size_t)(j0+lr)*H + k0 + lc);
    As[lc+0][lr]=av.x; As[lc+1][lr]=av.y; As[lc+2][lr]=av.z; As[lc+3][lr]=av.w;
    Bs[lc+0][lr]=bv.x; Bs[lc+1][lr]=bv.y; Bs[lc+2][lr]=bv.z; Bs[lc+3][lr]=bv.w;
    __syncthreads();
    #pragma unroll
    for (int kk=0; kk<16; ++kk){
      float a0=As[kk][ty*4+0], a1=As[kk][ty*4+1], a2=As[kk][ty*4+2], a3=As[kk][ty*4+3];
      float b0=Bs[kk][tx*4+0], b1=Bs[kk][tx*4+1], b2=Bs[kk][tx*4+2], b3=Bs[kk][tx*4+3];
      acc[0][0]=fmaf(a0,b0,acc[0][0]); acc[0][1]=fmaf(a0,b1,acc[0][1]);
      acc[0][2]=fmaf(a0,b2,acc[0][2]); acc[0][3]=fmaf(a0,b3,acc[0][3]);
      acc[1][0]=fmaf(a1,b0,acc[1][0]); acc[1][1]=fmaf(a1,b1,acc[1][1]);
      acc[1][2]=fmaf(a1,b2,acc[1][2]); acc[1][3]=fmaf(a1,b3,acc[1][3]);
      acc[2][0]=fmaf(a2,b0,acc[2][0]); acc[2][1]=fmaf(a2,b1,acc[2][1]);
      acc[2][2]=fmaf(a2,b2,acc[2][2]); acc[2][3]=fmaf(a2,b3,acc[2][3]);
      acc[3][0]=fmaf(a3,b0,acc[3][0]); acc[3][1]=fmaf(a3,b1,acc[3][1]);
      acc[3][2]=fmaf(a3,b2,acc[3][2]); acc[3][3]=fmaf(a3,b3,acc[3][3]);
    }
    __syncthreads();
  }

  #pragma unroll
  for (int u=0; u<4; ++u){
    float4 o;
    o.x = acc[u][0] + bias[j0+tx*4+0];
    o.y = acc[u][1] + bias[j0+tx*4+1];
    o.z = acc[u][2] + bias[j0+tx*4+2];
    o.w = acc[u][3] + bias[j0+tx*4+3];
    *(float4*)(C + (size_t)(m0+ty*4+u)*G3 + j0 + tx*4) = o;
  }
}

// XCD-local persistent scan, register-budgeted for 2 WGs/CU (16 waves/CU):
//  - 64 worker WGs per direction (bid%8==0 fwd, ==1 rev; others exit), so
//    with %8 round-robin XCD dispatch each direction co-locates on one XCD
//    (exactly 2 WGs x 8 waves per CU) and h flows through that XCD's L2.
//  - weights f16-packed: 48 v2f16 AGPRs + 6 bias AGPRs per lane; dots via
//    v_dot2_f32_f16 (fp32 accumulate). h stays fp32 except the dot operand.
//  - __launch_bounds__(512,4) forces total regs <=128/lane: worst case the
//    compiler spills (slow, recoverable) instead of halving occupancy
//    (deadlock, R7).
//  - polls alternate sc0 with every-4th sc0+sc1; producers dual-publish:
//    if co-location fails we degrade to the R3 cross-XCD path, never hang.
__global__ __launch_bounds__(512, 4) void scan_kernel(
  const float* __restrict__ gxF, const float* __restrict__ gxR,
  const float* __restrict__ WhF, const float* __restrict__ WhR,
  const float* __restrict__ bhF, const float* __restrict__ bhR,
  float* hFbuf, float* hRbuf, float* __restrict__ out)
{
  const int bid  = blockIdx.x;
  const int role = bid & 7;
  if (role >= 2) return;
  const int dir  = role;              // 0 fwd, 1 rev
  const int rank = bid >> 3;          // 0..63
  const int i0   = rank * 16;         // WG owns h[i0..i0+15]
  const int tid  = threadIdx.x;       // 0..511
  const int lane = tid & 63;
  const int wv   = tid >> 6;          // wave 0..7

  const float* gx  = dir ? gxR : gxF;
  const float* Whh = dir ? WhR : WhF;
  const float* bhh = dir ? bhR : bhF;
  float* hbuf      = dir ? hRbuf : hFbuf;

  const int ia = i0 + 2*wv;           // this wave's two h-elements
  const int ib = ia + 1;
  const int rows[6] = { ia, H+ia, 2*H+ia, ib, H+ib, 2*H+ib };

  // Pack weights to f16 pairs, park 48 packed words + 6 biases in AGPRs.
  // k-mapping: pair t (0..7) of row rr covers k = (t>>1)*256 + lane*4 + (t&1)*2 + {0,1}
  uint32_t wa[48];
  float    ba[6];
  #pragma unroll
  for (int rr=0; rr<6; ++rr){
    const float* wp = Whh + (size_t)rows[rr]*H;
    #pragma unroll
    for (int q=0; q<4; ++q){
      float4 w4 = *(const float4*)(wp + q*256 + lane*4);
      uint32_t u0 = pk_u(w4.x, w4.y);
      uint32_t u1 = pk_u(w4.z, w4.w);
      asm volatile("v_accvgpr_write_b32 %0, %1" : "=a"(wa[rr*8+q*2+0]) : "v"(u0));
      asm volatile("v_accvgpr_write_b32 %0, %1" : "=a"(wa[rr*8+q*2+1]) : "v"(u1));
    }
    float bb = bhh[rows[rr]];
    asm volatile("v_accvgpr_write_b32 %0, %1" : "=a"(ba[rr]) : "v"(bb));
  }

  __shared__ float    hs_f[2][H];       // fp32 h (for the z*h_prev term)
  __shared__ uint32_t hs_p[2][H/2];     // f16x2-packed h (dot operand)

  for (int s=0; s<SEQL; ++s){
    const int b = s & 1;
    const int t = dir ? (SEQL-1-s) : s;
    const float* gxt = gx + (size_t)t*G3;
    // h-independent loads issued ahead of the wait
    float g0 = gxt[ia], g1 = gxt[H+ia], g2 = gxt[2*H+ia];
    float g3 = gxt[ib], g4 = gxt[H+ib], g5 = gxt[2*H+ib];

    // poll h[s-1]: L2-scope fast path, coherence-point every 4th iteration
    if (tid < 256){
      float4 v;
      if (s == 0){
        v = make_float4(0.f,0.f,0.f,0.f);
      } else {
        const float* src = hbuf + (size_t)(s-1)*H + tid*4;
        int it = 0;
        for (;;){
          v = ((++it & 3) != 0) ? ld_l2(src) : ld_uc(src);
          if (!(v.x==SENT || v.y==SENT || v.z==SENT || v.w==SENT)) break;
        }
      }
      *(float4*)&hs_f[b][tid*4] = v;
      uint2 pk;
      pk.x = pk_u(v.x, v.y);
      pk.y = pk_u(v.z, v.w);
      *(uint2*)&hs_p[b][tid*2] = pk;
    }
    __syncthreads();

    // this lane's 8 packed h pairs (16 k-elements)
    uint32_t hp[8];
    #pragma unroll
    for (int q=0; q<4; ++q){
      uint2 u = *(const uint2*)&hs_p[b][q*128 + lane*2];
      hp[q*2+0] = u.x; hp[q*2+1] = u.y;
    }

    // 6 row-dots; weight AGPR reads per-row to cap live VGPRs
    float dots[6];
    #pragma unroll
    for (int rr=0; rr<6; ++rr){
      float acc = 0.f;
      #pragma unroll
      for (int tt=0; tt<8; ++tt){
        uint32_t wu;
        asm volatile("v_accvgpr_read_b32 %0, %1" : "=v"(wu) : "a"(wa[rr*8+tt]));
        acc = __builtin_amdgcn_fdot2(u_as_h2(wu), u_as_h2(hp[tt]), acc, false);
      }
      dots[rr] = acc;
    }
    // cross-lane reduce, 6 rows interleaved for ILP
    #pragma unroll
    for (int off=32; off>0; off>>=1){
      #pragma unroll
      for (int rr=0; rr<6; ++rr) dots[rr] += __shfl_xor(dots[rr], off);
    }
    #pragma unroll
    for (int rr=0; rr<6; ++rr){
      float bv;
      asm volatile("v_accvgpr_read_b32 %0, %1" : "=v"(bv) : "a"(ba[rr]));
      dots[rr] += bv;
    }

    const float hpa = hs_f[b][ia], hpb = hs_f[b][ib];

    float ra = sigmoidf_(g0 + dots[0]);
    float za = sigmoidf_(g1 + dots[1]);
    float na = tanhf    (g2 + ra*dots[2]);
    float hna = (1.f - za)*na + za*hpa;

    float rb = sigmoidf_(g3 + dots[3]);
    float zb = sigmoidf_(g4 + dots[4]);
    float nb = tanhf    (g5 + rb*dots[5]);
    float hnb = (1.f - zb)*nb + zb*hpb;

    if (lane == 0){
      float2 h2v = make_float2(hna, hnb);
      float* dst = hbuf + (size_t)s*H + ia;
      st_l2_2(dst, h2v);               // same-XCD fast path (updates local L2)
      st_uc_2(dst, h2v);               // coherence point (cross-XCD fallback)
      *(float2*)(out + (size_t)t*2048 + dir*H + ia) = h2v;
      if (s == SEQL-1){
        const size_t base = (size_t)SEQL*2048;
        *(float2*)(out + base + dir*H + ia)        = h2v;   // hidden
        *(float2*)(out + base + 2048 + dir*H + ia) = h2v;   // projected_output
      }
    }
    // single barrier/step: next iteration's pollers write the other buffer
  }
}

extern "C" void kernel_launch(void* const* d_in, const int* in_sizes, int n_in,
                              void* d_out, int out_size, void* d_ws, size_t ws_size,
                              hipStream_t stream)
{
  const int*   ids  = (const int*)  d_in[0];
  const float* emb  = (const float*)d_in[1];
  const float* WihF = (const float*)d_in[2];
  const float* WhhF = (const float*)d_in[3];
  const float* bihF = (const float*)d_in[4];
  const float* bhhF = (const float*)d_in[5];
  const float* WihR = (const float*)d_in[6];
  const float* WhhR = (const float*)d_in[7];
  const float* bihR = (const float*)d_in[8];
  const float* bhhR = (const float*)d_in[9];
  float* out = (float*)d_out;
  float* ws  = (float*)d_ws;

  float* embeds = ws;                       // 2048*1024
  float* gxF    = embeds + (size_t)SEQL*H;  // 2048*3072
  float* gxR    = gxF + (size_t)SEQL*G3;    // 2048*3072
  float* hF     = gxR + (size_t)SEQL*G3;    // 2048*1024
  float* hR     = hF + (size_t)SEQL*H;      // 2048*1024

  init_sent<<<4096, 256, 0, stream>>>(hF, 1048576);
  embed_kernel<<<SEQL, 256, 0, stream>>>(ids, emb, embeds);
  dim3 gg(96, 32);
  gemm_kernel<<<gg, 256, 0, stream>>>(embeds, WihF, WihR, bihF, bihR, gxF, gxR);
  scan_kernel<<<512, 512, 0, stream>>>(gxF, gxR, WhhF, WhhR, bhhF, bhhR, hF, hR, out);
}

// Round 11
// 8284.907 us; speedup vs baseline: 2.0395x; 2.0395x over previous
//
#include <hip/hip_runtime.h>
#include <math.h>

#define SEQL 2048
#define H 1024
#define G3 3072
#define SENT 1.0e30f

__device__ __forceinline__ float sigmoidf_(float x){ return 1.0f/(1.0f+expf(-x)); }

// Cache-bypassing 16B load; load AND waitcnt in ONE asm block (the only
// correct pattern — R10's split-block pipelined poll let the allocator
// spill the not-yet-written dest regs and returned garbage).
__device__ __forceinline__ float4 ld_uc(const float* p){
  float4 r;
  asm volatile("global_load_dwordx4 %0, %1, off sc0 sc1\n\t"
               "s_waitcnt vmcnt(0)"
               : "=&v"(r) : "v"(p) : "memory");
  return r;
}
__device__ __forceinline__ int ok4(float4 v){
  return !(v.x==SENT || v.y==SENT || v.z==SENT || v.w==SENT);
}
// Cache-bypassing 8B store (fire-and-forget; visible at coherence point).
__device__ __forceinline__ void st_uc_2(float* p, float2 v){
  asm volatile("global_store_dwordx2 %0, %1, off sc0 sc1"
               :: "v"(p), "v"(v) : "memory");
}

__global__ __launch_bounds__(256) void init_sent(float* p, int n4){
  int i = blockIdx.x*256 + threadIdx.x;
  if (i < n4) ((float4*)p)[i] = make_float4(SENT,SENT,SENT,SENT);
}

__global__ __launch_bounds__(256) void embed_kernel(const int* __restrict__ ids,
                                                    const float* __restrict__ emb,
                                                    float* __restrict__ out){
  int t = blockIdx.x;
  int id = ids[t];
  const float4* src = (const float4*)(emb + (size_t)id*H);
  float4* dst = (float4*)(out + (size_t)t*H);
  float4 v = (id == 1) ? make_float4(0.f,0.f,0.f,0.f) : src[threadIdx.x];
  dst[threadIdx.x] = v;
}

__global__ __launch_bounds__(256) void gemm_kernel(const float* __restrict__ A,
  const float* __restrict__ WF, const float* __restrict__ WR,
  const float* __restrict__ bF, const float* __restrict__ bR,
  float* __restrict__ gxF, float* __restrict__ gxR)
{
  __shared__ float As[16][68];
  __shared__ float Bs[16][68];
  const int tid = threadIdx.x;
  const int n0 = blockIdx.x * 64;
  const int m0 = blockIdx.y * 64;
  const int dir = (n0 >= G3);
  const float* B    = dir ? WR : WF;
  const float* bias = dir ? bR : bF;
  float* C          = dir ? gxR : gxF;
  const int j0 = dir ? (n0 - G3) : n0;

  const int lr = tid >> 2;
  const int lc = (tid & 3) * 4;
  const int tx = tid & 15;
  const int ty = tid >> 4;

  float acc[4][4] = {};

  for (int k0 = 0; k0 < H; k0 += 16){
    float4 av = *(const float4*)(A + (size_t)(m0+lr)*H + k0 + lc);
    float4 bv = *(const float4*)(B + (size_t)(j0+lr)*H + k0 + lc);
    As[lc+0][lr]=av.x; As[lc+1][lr]=av.y; As[lc+2][lr]=av.z; As[lc+3][lr]=av.w;
    Bs[lc+0][lr]=bv.x; Bs[lc+1][lr]=bv.y; Bs[lc+2][lr]=bv.z; Bs[lc+3][lr]=bv.w;
    __syncthreads();
    #pragma unroll
    for (int kk=0; kk<16; ++kk){
      float a0=As[kk][ty*4+0], a1=As[kk][ty*4+1], a2=As[kk][ty*4+2], a3=As[kk][ty*4+3];
      float b0=Bs[kk][tx*4+0], b1=Bs[kk][tx*4+1], b2=Bs[kk][tx*4+2], b3=Bs[kk][tx*4+3];
      acc[0][0]=fmaf(a0,b0,acc[0][0]); acc[0][1]=fmaf(a0,b1,acc[0][1]);
      acc[0][2]=fmaf(a0,b2,acc[0][2]); acc[0][3]=fmaf(a0,b3,acc[0][3]);
      acc[1][0]=fmaf(a1,b0,acc[1][0]); acc[1][1]=fmaf(a1,b1,acc[1][1]);
      acc[1][2]=fmaf(a1,b2,acc[1][2]); acc[1][3]=fmaf(a1,b3,acc[1][3]);
      acc[2][0]=fmaf(a2,b0,acc[2][0]); acc[2][1]=fmaf(a2,b1,acc[2][1]);
      acc[2][2]=fmaf(a2,b2,acc[2][2]); acc[2][3]=fmaf(a2,b3,acc[2][3]);
      acc[3][0]=fmaf(a3,b0,acc[3][0]); acc[3][1]=fmaf(a3,b1,acc[3][1]);
      acc[3][2]=fmaf(a3,b2,acc[3][2]); acc[3][3]=fmaf(a3,b3,acc[3][3]);
    }
    __syncthreads();
  }

  #pragma unroll
  for (int u=0; u<4; ++u){
    float4 o;
    o.x = acc[u][0] + bias[j0+tx*4+0];
    o.y = acc[u][1] + bias[j0+tx*4+1];
    o.z = acc[u][2] + bias[j0+tx*4+2];
    o.w = acc[u][3] + bias[j0+tx*4+3];
    *(float4*)(C + (size_t)(m0+ty*4+u)*G3 + j0 + tx*4) = o;
  }
}

// Persistent scan, R3 skeleton + two safe fixes:
//  (1) weight loads (48 fp32/lane, L2-resident) issued BEFORE the poll each
//      step; the poll's internal vmcnt(0) drains them under the wait;
//  (2) consolidated publish: LDS gather + ONE thread stores the WG's 32B
//      chunk (128 publish events/dir instead of 1024); own chunk via LDS.
// Poll itself is the proven single-asm-block load+wait (R2-R9 pattern).
__global__ __launch_bounds__(512, 2) void scan_kernel(
  const float* __restrict__ gxF, const float* __restrict__ gxR,
  const float* __restrict__ WhF, const float* __restrict__ WhR,
  const float* __restrict__ bhF, const float* __restrict__ bhR,
  float* hFbuf, float* hRbuf, float* __restrict__ out)
{
  const int wgid = blockIdx.x;        // 0..255
  const int dir  = wgid >> 7;         // 0 fwd, 1 rev
  const int d    = wgid & 127;        // chunk id
  const int i0   = d * 8;
  const int tid  = threadIdx.x;       // 0..511
  const int lane = tid & 63;
  const int wv   = tid >> 6;          // wave 0..7; each wave owns h[ia]

  const float* gx  = dir ? gxR : gxF;
  const float* Whh = dir ? WhR : WhF;
  const float* bhh = dir ? bhR : bhF;
  float* hbuf      = dir ? hRbuf : hFbuf;

  const int ia = i0 + wv;
  const float* wp0 = Whh + (size_t)(ia)*H;
  const float* wp1 = Whh + (size_t)(H+ia)*H;
  const float* wp2 = Whh + (size_t)(2*H+ia)*H;
  const float b0v = bhh[ia], b1v = bhh[H+ia], b2v = bhh[2*H+ia];

  __shared__ float hs[H];
  __shared__ float hstage[2][8];

  for (int s=0; s<SEQL; ++s){
    const int t = dir ? (SEQL-1-s) : s;
    const float* gxt = gx + (size_t)t*G3;
    // h-independent loads issued ahead of the wait (gx + weights)
    float g0 = gxt[ia], g1 = gxt[H+ia], g2 = gxt[2*H+ia];
    float4 w0[4], w1[4], w2[4];
    #pragma unroll
    for (int q=0; q<4; ++q){
      w0[q] = *(const float4*)(wp0 + q*256 + lane*4);
      w1[q] = *(const float4*)(wp1 + q*256 + lane*4);
      w2[q] = *(const float4*)(wp2 + q*256 + lane*4);
    }

    // acquire h[s-1] into LDS (256 pollers x 16B; own chunk from LDS stage)
    if (tid < 256){
      float4 v;
      if (s == 0)               v = make_float4(0.f,0.f,0.f,0.f);
      else if ((tid >> 1) == d) v = *(const float4*)&hstage[(s-1)&1][(tid&1)*4];
      else {
        const float* src = hbuf + (size_t)(s-1)*H + tid*4;
        do { v = ld_uc(src); } while (!ok4(v));
      }
      *(float4*)&hs[tid*4] = v;
    }
    __syncthreads();                  // B1: hs ready

    float hv[16];
    #pragma unroll
    for (int q=0; q<4; ++q){
      float4 hq = *(const float4*)&hs[q*256 + lane*4];
      hv[q*4+0]=hq.x; hv[q*4+1]=hq.y; hv[q*4+2]=hq.z; hv[q*4+3]=hq.w;
    }

    float d0=0.f, d1=0.f, d2=0.f;
    #pragma unroll
    for (int q=0; q<4; ++q){
      const float* a0=(const float*)&w0[q];
      const float* a1=(const float*)&w1[q];
      const float* a2=(const float*)&w2[q];
      #pragma unroll
      for (int j=0; j<4; ++j){
        float hj = hv[q*4+j];
        d0 = fmaf(a0[j], hj, d0);
        d1 = fmaf(a1[j], hj, d1);
        d2 = fmaf(a2[j], hj, d2);
      }
    }
    #pragma unroll
    for (int off=32; off>0; off>>=1){
      d0 += __shfl_xor(d0, off);
      d1 += __shfl_xor(d1, off);
      d2 += __shfl_xor(d2, off);
    }

    const float hp = hs[ia];
    float r  = sigmoidf_(g0 + d0 + b0v);
    float z  = sigmoidf_(g1 + d1 + b1v);
    float n  = tanhf    (g2 + r*(d2 + b2v));
    float hn = (1.f - z)*n + z*hp;

    if (lane == 0){
      hstage[s&1][wv] = hn;
      out[(size_t)t*2048 + dir*H + ia] = hn;
      if (s == SEQL-1){
        const size_t base = (size_t)SEQL*2048;
        out[base + dir*H + ia]        = hn;   // hidden
        out[base + 2048 + dir*H + ia] = hn;   // projected_output
      }
    }
    __syncthreads();                  // B2: hstage complete, hs reads done

    // consolidated publish: one 32B chunk per WG (4 x 8B UC stores, one line)
    if (tid == 0){
      float* dst = hbuf + (size_t)s*H + i0;
      const float* hv8 = &hstage[s&1][0];
      st_uc_2(dst+0, make_float2(hv8[0], hv8[1]));
      st_uc_2(dst+2, make_float2(hv8[2], hv8[3]));
      st_uc_2(dst+4, make_float2(hv8[4], hv8[5]));
      st_uc_2(dst+6, make_float2(hv8[6], hv8[7]));
    }
  }
}

extern "C" void kernel_launch(void* const* d_in, const int* in_sizes, int n_in,
                              void* d_out, int out_size, void* d_ws, size_t ws_size,
                              hipStream_t stream)
{
  const int*   ids  = (const int*)  d_in[0];
  const float* emb  = (const float*)d_in[1];
  const float* WihF = (const float*)d_in[2];
  const float* WhhF = (const float*)d_in[3];
  const float* bihF = (const float*)d_in[4];
  const float* bhhF = (const float*)d_in[5];
  const float* WihR = (const float*)d_in[6];
  const float* WhhR = (const float*)d_in[7];
  const float* bihR = (const float*)d_in[8];
  const float* bhhR = (const float*)d_in[9];
  float* out = (float*)d_out;
  float* ws  = (float*)d_ws;

  float* embeds = ws;                       // 2048*1024
  float* gxF    = embeds + (size_t)SEQL*H;  // 2048*3072
  float* gxR    = gxF + (size_t)SEQL*G3;    // 2048*3072
  float* hF     = gxR + (size_t)SEQL*G3;    // 2048*1024
  float* hR     = hF + (size_t)SEQL*H;      // 2048*1024

  init_sent<<<4096, 256, 0, stream>>>(hF, 1048576);
  embed_kernel<<<SEQL, 256, 0, stream>>>(ids, emb, embeds);
  dim3 gg(96, 32);
  gemm_kernel<<<gg, 256, 0, stream>>>(embeds, WihF, WihR, bihF, bihR, gxF, gxR);
  scan_kernel<<<256, 512, 0, stream>>>(gxF, gxR, WhhF, WhhR, bhhF, bhhR, hF, hR, out);
}

// Round 12
// 6477.440 us; speedup vs baseline: 2.6086x; 1.2790x over previous
//
#include <hip/hip_runtime.h>
#include <math.h>

#define SEQL 2048
#define H 1024
#define G3 3072
#define SENT 1.0e30f

typedef __fp16   fp16x2  __attribute__((ext_vector_type(2)));
typedef _Float16 half2_t __attribute__((ext_vector_type(2)));

__device__ __forceinline__ float sigmoidf_(float x){ return 1.0f/(1.0f+expf(-x)); }

__device__ __forceinline__ uint32_t pk_u(float a, float b){
  fp16x2 h = __builtin_amdgcn_cvt_pkrtz(a, b);
  union{fp16x2 h; uint32_t u;} c; c.h = h; return c.u;
}
__device__ __forceinline__ half2_t u_as_h2(uint32_t x){
  union{half2_t h; uint32_t u;} c; c.u = x; return c.h;
}

// Cache-bypassing 16B load; load AND waitcnt in ONE asm block (R10 lesson:
// split-block polls let the allocator spill not-yet-written dest regs).
__device__ __forceinline__ float4 ld_uc(const float* p){
  float4 r;
  asm volatile("global_load_dwordx4 %0, %1, off sc0 sc1\n\t"
               "s_waitcnt vmcnt(0)"
               : "=&v"(r) : "v"(p) : "memory");
  return r;
}
__device__ __forceinline__ int ok4(float4 v){
  return !(v.x==SENT || v.y==SENT || v.z==SENT || v.w==SENT);
}
// Cache-bypassing 4B store (fire-and-forget; visible at coherence point).
__device__ __forceinline__ void st_uc_1(float* p, float v){
  asm volatile("global_store_dword %0, %1, off sc0 sc1"
               :: "v"(p), "v"(v) : "memory");
}

__global__ __launch_bounds__(256) void init_sent(float* p, int n4){
  int i = blockIdx.x*256 + threadIdx.x;
  if (i < n4) ((float4*)p)[i] = make_float4(SENT,SENT,SENT,SENT);
}

__global__ __launch_bounds__(256) void embed_kernel(const int* __restrict__ ids,
                                                    const float* __restrict__ emb,
                                                    float* __restrict__ out){
  int t = blockIdx.x;
  int id = ids[t];
  const float4* src = (const float4*)(emb + (size_t)id*H);
  float4* dst = (float4*)(out + (size_t)t*H);
  float4 v = (id == 1) ? make_float4(0.f,0.f,0.f,0.f) : src[threadIdx.x];
  dst[threadIdx.x] = v;
}

__global__ __launch_bounds__(256) void gemm_kernel(const float* __restrict__ A,
  const float* __restrict__ WF, const float* __restrict__ WR,
  const float* __restrict__ bF, const float* __restrict__ bR,
  float* __restrict__ gxF, float* __restrict__ gxR)
{
  __shared__ float As[16][68];
  __shared__ float Bs[16][68];
  const int tid = threadIdx.x;
  const int n0 = blockIdx.x * 64;
  const int m0 = blockIdx.y * 64;
  const int dir = (n0 >= G3);
  const float* B    = dir ? WR : WF;
  const float* bias = dir ? bR : bF;
  float* C          = dir ? gxR : gxF;
  const int j0 = dir ? (n0 - G3) : n0;

  const int lr = tid >> 2;
  const int lc = (tid & 3) * 4;
  const int tx = tid & 15;
  const int ty = tid >> 4;

  float acc[4][4] = {};

  for (int k0 = 0; k0 < H; k0 += 16){
    float4 av = *(const float4*)(A + (size_t)(m0+lr)*H + k0 + lc);
    float4 bv = *(const float4*)(B + (size_t)(j0+lr)*H + k0 + lc);
    As[lc+0][lr]=av.x; As[lc+1][lr]=av.y; As[lc+2][lr]=av.z; As[lc+3][lr]=av.w;
    Bs[lc+0][lr]=bv.x; Bs[lc+1][lr]=bv.y; Bs[lc+2][lr]=bv.z; Bs[lc+3][lr]=bv.w;
    __syncthreads();
    #pragma unroll
    for (int kk=0; kk<16; ++kk){
      float a0=As[kk][ty*4+0], a1=As[kk][ty*4+1], a2=As[kk][ty*4+2], a3=As[kk][ty*4+3];
      float b0=Bs[kk][tx*4+0], b1=Bs[kk][tx*4+1], b2=Bs[kk][tx*4+2], b3=Bs[kk][tx*4+3];
      acc[0][0]=fmaf(a0,b0,acc[0][0]); acc[0][1]=fmaf(a0,b1,acc[0][1]);
      acc[0][2]=fmaf(a0,b2,acc[0][2]); acc[0][3]=fmaf(a0,b3,acc[0][3]);
      acc[1][0]=fmaf(a1,b0,acc[1][0]); acc[1][1]=fmaf(a1,b1,acc[1][1]);
      acc[1][2]=fmaf(a1,b2,acc[1][2]); acc[1][3]=fmaf(a1,b3,acc[1][3]);
      acc[2][0]=fmaf(a2,b0,acc[2][0]); acc[2][1]=fmaf(a2,b1,acc[2][1]);
      acc[2][2]=fmaf(a2,b2,acc[2][2]); acc[2][3]=fmaf(a2,b3,acc[2][3]);
      acc[3][0]=fmaf(a3,b0,acc[3][0]); acc[3][1]=fmaf(a3,b1,acc[3][1]);
      acc[3][2]=fmaf(a3,b2,acc[3][2]); acc[3][3]=fmaf(a3,b3,acc[3][3]);
    }
    __syncthreads();
  }

  #pragma unroll
  for (int u=0; u<4; ++u){
    float4 o;
    o.x = acc[u][0] + bias[j0+tx*4+0];
    o.y = acc[u][1] + bias[j0+tx*4+1];
    o.z = acc[u][2] + bias[j0+tx*4+2];
    o.w = acc[u][3] + bias[j0+tx*4+3];
    *(float4*)(C + (size_t)(m0+ty*4+u)*G3 + j0 + tx*4) = o;
  }
}

// Persistent scan, weights in LDS (f16-packed):
//  - one-time stage of this WG's 24 W_hh rows into 48KB LDS; per step the
//    dots read weights from LDS — weight access is off the global-memory
//    critical path AND immune to the register allocator (R3/R4/R11 lesson:
//    compiler never keeps a 48-float weight array live across the poll).
//  - dots via v_dot2_f32_f16 (f16 w & h, fp32 accumulate; R9 validated
//    absmax 0.00195); carried h state stays fp32 (hs_f).
//  - exchange: R3-proven publish-ASAP (lane0 st_uc right after computing)
//    + uniform sentinel poll by 256 tids (own chunk polled like any other —
//    it arrives in the same RTT window, no extra barrier needed).
__global__ __launch_bounds__(512, 2) void scan_kernel(
  const float* __restrict__ gxF, const float* __restrict__ gxR,
  const float* __restrict__ WhF, const float* __restrict__ WhR,
  const float* __restrict__ bhF, const float* __restrict__ bhR,
  float* hFbuf, float* hRbuf, float* __restrict__ out)
{
  const int wgid = blockIdx.x;        // 0..255
  const int dir  = wgid >> 7;         // 0 fwd, 1 rev
  const int d    = wgid & 127;        // chunk id
  const int i0   = d * 8;
  const int tid  = threadIdx.x;       // 0..511
  const int lane = tid & 63;
  const int wv   = tid >> 6;          // wave 0..7; wave owns h[i0+wv]

  const float* gx  = dir ? gxR : gxF;
  const float* Whh = dir ? WhR : WhF;
  const float* bhh = dir ? bhR : bhF;
  float* hbuf      = dir ? hRbuf : hFbuf;

  const int ia = i0 + wv;

  __shared__ uint32_t wlds[24][512];   // f16x2-packed weights: row g*8+e
  __shared__ float    hs_f[2][H];      // fp32 h (carried-state term)
  __shared__ uint32_t hs_p[2][H/2];    // f16x2-packed h (dot operand)

  // one-time stage: 24 rows x 1024 f32 -> f16x2 LDS (6144 float4 loads)
  for (int idx = tid; idx < 6144; idx += 512){
    int r  = idx >> 8;                 // 0..23
    int c4 = idx & 255;                // float4 column
    int grow = (r >> 3)*H + i0 + (r & 7);
    float4 w4 = *(const float4*)(Whh + (size_t)grow*H + c4*4);
    uint2 p2; p2.x = pk_u(w4.x, w4.y); p2.y = pk_u(w4.z, w4.w);
    *(uint2*)&wlds[r][c4*2] = p2;
  }
  const float b0v = bhh[ia], b1v = bhh[H+ia], b2v = bhh[2*H+ia];

  for (int s=0; s<SEQL; ++s){
    const int b = s & 1;
    const int t = dir ? (SEQL-1-s) : s;
    const float* gxt = gx + (size_t)t*G3;
    // h-independent gx loads issued ahead of the wait
    float g0 = gxt[ia], g1 = gxt[H+ia], g2 = gxt[2*H+ia];

    // acquire h[s-1] (256 pollers x 16B, uniform incl. own chunk)
    if (tid < 256){
      float4 v;
      if (s == 0){
        v = make_float4(0.f,0.f,0.f,0.f);
      } else {
        const float* src = hbuf + (size_t)(s-1)*H + tid*4;
        do { v = ld_uc(src); } while (!ok4(v));
      }
      *(float4*)&hs_f[b][tid*4] = v;
      uint2 p2; p2.x = pk_u(v.x, v.y); p2.y = pk_u(v.z, v.w);
      *(uint2*)&hs_p[b][tid*2] = p2;
    }
    __syncthreads();                  // hs + (first iter) wlds ready

    // dots from LDS: 3 rows x 16 k-elems per lane, fdot2 pairs
    float d0=0.f, d1=0.f, d2=0.f;
    #pragma unroll
    for (int q=0; q<4; ++q){
      uint2 hq = *(const uint2*)&hs_p[b][q*128 + lane*2];
      uint2 a0 = *(const uint2*)&wlds[     wv][q*128 + lane*2];
      uint2 a1 = *(const uint2*)&wlds[ 8 + wv][q*128 + lane*2];
      uint2 a2 = *(const uint2*)&wlds[16 + wv][q*128 + lane*2];
      d0 = __builtin_amdgcn_fdot2(u_as_h2(a0.x), u_as_h2(hq.x), d0, false);
      d0 = __builtin_amdgcn_fdot2(u_as_h2(a0.y), u_as_h2(hq.y), d0, false);
      d1 = __builtin_amdgcn_fdot2(u_as_h2(a1.x), u_as_h2(hq.x), d1, false);
      d1 = __builtin_amdgcn_fdot2(u_as_h2(a1.y), u_as_h2(hq.y), d1, false);
      d2 = __builtin_amdgcn_fdot2(u_as_h2(a2.x), u_as_h2(hq.x), d2, false);
      d2 = __builtin_amdgcn_fdot2(u_as_h2(a2.y), u_as_h2(hq.y), d2, false);
    }
    #pragma unroll
    for (int off=32; off>0; off>>=1){
      d0 += __shfl_xor(d0, off);
      d1 += __shfl_xor(d1, off);
      d2 += __shfl_xor(d2, off);
    }

    const float hp = hs_f[b][ia];
    float r  = sigmoidf_(g0 + d0 + b0v);
    float z  = sigmoidf_(g1 + d1 + b1v);
    float n  = tanhf    (g2 + r*(d2 + b2v));
    float hn = (1.f - z)*n + z*hp;

    if (lane == 0){
      st_uc_1(hbuf + (size_t)s*H + ia, hn);   // publish ASAP
      out[(size_t)t*2048 + dir*H + ia] = hn;
      if (s == SEQL-1){
        const size_t base = (size_t)SEQL*2048;
        out[base + dir*H + ia]        = hn;   // hidden
        out[base + 2048 + dir*H + ia] = hn;   // projected_output
      }
    }
    __syncthreads();                  // hs reads done before next overwrite
  }
}

extern "C" void kernel_launch(void* const* d_in, const int* in_sizes, int n_in,
                              void* d_out, int out_size, void* d_ws, size_t ws_size,
                              hipStream_t stream)
{
  const int*   ids  = (const int*)  d_in[0];
  const float* emb  = (const float*)d_in[1];
  const float* WihF = (const float*)d_in[2];
  const float* WhhF = (const float*)d_in[3];
  const float* bihF = (const float*)d_in[4];
  const float* bhhF = (const float*)d_in[5];
  const float* WihR = (const float*)d_in[6];
  const float* WhhR = (const float*)d_in[7];
  const float* bihR = (const float*)d_in[8];
  const float* bhhR = (const float*)d_in[9];
  float* out = (float*)d_out;
  float* ws  = (float*)d_ws;

  float* embeds = ws;                       // 2048*1024
  float* gxF    = embeds + (size_t)SEQL*H;  // 2048*3072
  float* gxR    = gxF + (size_t)SEQL*G3;    // 2048*3072
  float* hF     = gxR + (size_t)SEQL*G3;    // 2048*1024
  float* hR     = hF + (size_t)SEQL*H;      // 2048*1024

  init_sent<<<4096, 256, 0, stream>>>(hF, 1048576);
  embed_kernel<<<SEQL, 256, 0, stream>>>(ids, emb, embeds);
  dim3 gg(96, 32);
  gemm_kernel<<<gg, 256, 0, stream>>>(embeds, WihF, WihR, bihF, bihR, gxF, gxR);
  scan_kernel<<<256, 512, 0, stream>>>(gxF, gxR, WhhF, WhhR, bhhF, bhhR, hF, hR, out);
}